// Round 18
// baseline (122.458 us; speedup 1.0000x reference)
//
#include <hip/hip_runtime.h>

#define NB 4
#define SEQ 4096
#define DIMK 1024
#define DKV 128
#define NS (NB * SEQ)
#define SCALE 0.08838834764831845f   // 1/sqrt(128)

typedef float  f32x4  __attribute__((ext_vector_type(4)));
typedef float  f32x16 __attribute__((ext_vector_type(16)));
typedef _Float16 f16x8 __attribute__((ext_vector_type(8)));
typedef _Float16 f16x4 __attribute__((ext_vector_type(4)));

static __device__ __forceinline__ int pkrtz(float a, float b) {
    auto h = __builtin_amdgcn_cvt_pkrtz(a, b);   // __fp16 ext_vector(2)
    return __builtin_bit_cast(int, h);
}

// async global->LDS, 16B per lane; LDS dest = wave-uniform base + lane*16 (linear)
static __device__ __forceinline__ void gll16(const void* g, void* l) {
    __builtin_amdgcn_global_load_lds((const __attribute__((address_space(1))) char*)g,
                                     (__attribute__((address_space(3))) char*)l, 16, 0, 0);
}

// ---------------- kernel 0: transpose W -> f16 WT[3][128][1024] ----------------
__global__ void prep_wt(const float* __restrict__ Wq, const float* __restrict__ Wk,
                        const float* __restrict__ Wv, _Float16* __restrict__ WT) {
    int tid = blockIdx.x * 256 + threadIdx.x;
    int n  = tid & 127;
    int k  = (tid >> 7) & 1023;
    int w3 = tid >> 17;
    const float* W = (w3 == 0) ? Wq : (w3 == 1) ? Wk : Wv;
    WT[((size_t)w3 * 128 + n) * 1024 + k] = (_Float16)W[(size_t)k * 128 + n];
}

// ---------------- kernel 1: QKV projection + XCD sibling swizzle ----------------
// r17 post-mortem: X (64MB) was fetched 3x from HBM because the 3 w3-siblings of
// each X-tile round-robin onto different XCDs. Chunked swizzle (cpx=96) keeps the
// siblings on ONE XCD -> X served once from HBM, twice from its L2.
__global__ __launch_bounds__(256, 2) void qkv_proj(
    const float* __restrict__ X,
    const float* __restrict__ bq, const float* __restrict__ bk, const float* __restrict__ bv,
    const _Float16* __restrict__ WT,
    _Float16* __restrict__ Qh, _Float16* __restrict__ Kh, _Float16* __restrict__ VTh) {

    __shared__ __attribute__((aligned(16))) char WTs[2][128 * 144];   // 36864 B
    const int t = threadIdx.x;
    const int w = t >> 6, l = t & 63;
    const int lrow = l & 15, lg = l >> 4;
    const int work = (blockIdx.x & 7) * 96 + (blockIdx.x >> 3);   // grid 768 = 8 x 96
    const int w3   = work % 3;
    const int tile = work / 3;
    const int r0 = tile * 64;

    f32x4 acc[8] = {};
    const float* xrow = X + (size_t)(r0 + w * 16 + lrow) * DIMK;
    const _Float16* Wbase = WT + (size_t)w3 * 128 * 1024;

    const int srow = t >> 3, spart = t & 7;        // + 32 rows per chunk index

    {
        int4 wreg[4];
        #pragma unroll
        for (int i = 0; i < 4; ++i)
            wreg[i] = *(const int4*)(Wbase + (size_t)(srow + 32 * i) * 1024 + spart * 8);
        #pragma unroll
        for (int i = 0; i < 4; ++i)
            *(int4*)(WTs[0] + (srow + 32 * i) * 144 + spart * 16) = wreg[i];
    }
    float4 xc0 = *(const float4*)(xrow + lg * 8);
    float4 xc1 = *(const float4*)(xrow + lg * 8 + 4);
    float4 xc2 = *(const float4*)(xrow + 32 + lg * 8);
    float4 xc3 = *(const float4*)(xrow + 32 + lg * 8 + 4);
    __syncthreads();

    for (int kt = 0; kt < 16; ++kt) {
        const int cur = kt & 1;
        const int k0n = ((kt + 1) & 15) * 64;      // wrap: last-iter data unused
        float4 xn0 = *(const float4*)(xrow + k0n + lg * 8);
        float4 xn1 = *(const float4*)(xrow + k0n + lg * 8 + 4);
        float4 xn2 = *(const float4*)(xrow + k0n + 32 + lg * 8);
        float4 xn3 = *(const float4*)(xrow + k0n + 32 + lg * 8 + 4);
        int4 wreg[4];
        #pragma unroll
        for (int i = 0; i < 4; ++i)
            wreg[i] = *(const int4*)(Wbase + (size_t)(srow + 32 * i) * 1024 + k0n + spart * 8);

        #pragma unroll
        for (int kk = 0; kk < 2; ++kk) {
            f16x8 a;
            float4 u = kk ? xc2 : xc0, v = kk ? xc3 : xc1;
            a[0] = (_Float16)u.x; a[1] = (_Float16)u.y; a[2] = (_Float16)u.z; a[3] = (_Float16)u.w;
            a[4] = (_Float16)v.x; a[5] = (_Float16)v.y; a[6] = (_Float16)v.z; a[7] = (_Float16)v.w;
            #pragma unroll
            for (int n = 0; n < 8; ++n) {
                f16x8 bf = *(const f16x8*)(WTs[cur] + (n * 16 + lrow) * 144 +
                                           kk * 64 + lg * 16);
                acc[n] = __builtin_amdgcn_mfma_f32_16x16x32_f16(a, bf, acc[n], 0, 0, 0);
            }
        }
        #pragma unroll
        for (int i = 0; i < 4; ++i)
            *(int4*)(WTs[cur ^ 1] + (srow + 32 * i) * 144 + spart * 16) = wreg[i];
        __syncthreads();
        xc0 = xn0; xc1 = xn1; xc2 = xn2; xc3 = xn3;
    }

    const float* bias = (w3 == 0) ? bq : (w3 == 1) ? bk : bv;
    #pragma unroll
    for (int n = 0; n < 8; ++n) {
        int col = n * 16 + lrow;
        float bv_ = bias[col];
        #pragma unroll
        for (int j = 0; j < 4; ++j) {
            int grow = r0 + w * 16 + lg * 4 + j;
            float val = acc[n][j] + bv_;
            if (w3 == 0) {
                Qh[(size_t)grow * DKV + col] = (_Float16)(val * SCALE);
            } else if (w3 == 1) {
                Kh[(size_t)grow * DKV + col] = (_Float16)val;
            } else {
                int b = grow >> 12, sp = grow & 4095;
                VTh[((size_t)b * DKV + col) * SEQ + sp] = (_Float16)val;
            }
        }
    }
}

// ---------------- kernel 2: flash attention, kv-split + time-muxed 8KB/wave LDS ----------------
// r10..r17 all pinned at 76us = 8 waves/CU (2/SIMD): grid-starved (B*H=4) AND
// 16KB/wave LDS. Fix BOTH: kv-split nsplit across blocks (grid 512*nsplit) and K/V
// time-share ONE 8KB buffer per wave -> LDS 33KB/block -> 4 blocks/CU = 16 waves/CU.
// Schedule (r17-proven gll ordering, single buffer):
//   vmcnt(0)[K here] -> QK^T -> lgkm(0) -> V-gll(same buf) -> softmax
//   -> vmcnt(0)[V here] -> PV -> lgkm(0) -> K-gll(next)
// Split s=0 partial -> out (f32); s=1 -> O1h f16 + (m,l) stats; combine kernel merges.
// Fallback nsplit=1 (ws too small): direct normalized write, grid 512.
__global__ __launch_bounds__(256, 2) void attn_kernel(
    const _Float16* __restrict__ Qh, const _Float16* __restrict__ Kh,
    const _Float16* __restrict__ VTh, float* __restrict__ out,
    _Float16* __restrict__ O1h, float* __restrict__ ml,
    int nsplit, int kps) {

    __shared__ __attribute__((aligned(16))) char lds[33280];

    const int t = threadIdx.x;
    const int w = t >> 6, l = t & 63;
    const int lq = l & 31;          // q column within tile
    const int hi = l >> 5;

    // XCD-chunked swizzle; work = (b*nsplit + s)*128 + qt so one XCD's chunk shares
    // a (b, key-range) K/V slice (~1MB) in its L2 across 128 q-tiles.
    const int cpx = gridDim.x >> 3;
    const int work = (blockIdx.x & 7) * cpx + (blockIdx.x >> 3);
    const int bs = work >> 7;
    const int qt = work & 127;
    const int b  = (nsplit == 2) ? (bs >> 1) : bs;
    const int s  = (nsplit == 2) ? (bs & 1) : 0;
    const int q0 = qt * 32;

    char* KVw = lds + w * 8192;          // K view: [32][128] f16 swz (row&15)<<4
                                         // V view: [128][32] f16 chunk-XOR (dv>>1)&3

    f16x8 qf[8];
    #pragma unroll
    for (int c = 0; c < 8; ++c)
        qf[c] = *(const f16x8*)(Qh + (size_t)(b * SEQ + q0 + lq) * DKV + c * 16 + hi * 8);

    f32x16 o[4] = {};                    // O^T: 4 dv-tiles of 32, q = lq
    float m = -INFINITY, lsum = 0.f;

    const int wkeys = kps >> 2;          // keys per wave
    const int kts = wkeys >> 5;          // iterations (KVBLK=32)
    const int koff0 = s * kps + w * wkeys;
    const _Float16* Kbase = Kh + (size_t)(b * SEQ + koff0) * DKV;
    const _Float16* Vbase = VTh + (size_t)b * DKV * SEQ + koff0;

    const int krow_ = l >> 4;            // + 4 per K-chunk
    const int vdv_  = l >> 2;            // + 16 per V-chunk

#define STAGE_K(KOFF) {                                                                   \
        _Pragma("unroll")                                                                 \
        for (int i = 0; i < 8; ++i) {                                                     \
            int row = 4 * i + krow_;                                                      \
            int part = (l & 15) ^ (row & 15);                                             \
            gll16(Kbase + (size_t)((KOFF) + row) * DKV + part * 8, KVw + i * 1024);       \
        }                                                                                 \
    }
#define STAGE_V(KOFF) {                                                                   \
        _Pragma("unroll")                                                                 \
        for (int i = 0; i < 8; ++i) {                                                     \
            int dv = 16 * i + vdv_;                                                       \
            int p = (l & 3) ^ ((dv >> 1) & 3);                                            \
            gll16(Vbase + (size_t)dv * SEQ + (KOFF) + p * 8, KVw + i * 1024);             \
        }                                                                                 \
    }

    STAGE_K(0)

    for (int kt = 0; kt < kts; ++kt) {
        const int k0 = kt * 32;
        const int knext = (kt + 1 == kts) ? 0 : (kt + 1) * 32;   // wrap: data unused

        asm volatile("s_waitcnt vmcnt(0)" ::: "memory");   // K tile landed
        __builtin_amdgcn_sched_barrier(0);

        // ---- S^T = K Q^T : two independent 4-deep MFMA chains ----
        f32x16 sa = {}, sb = {};
        #pragma unroll
        for (int c = 0; c < 4; ++c) {
            f16x8 kfa = *(const f16x8*)(KVw + lq * 256 +
                                        (((2 * c + hi) * 16) ^ ((lq & 15) << 4)));
            f16x8 kfb = *(const f16x8*)(KVw + lq * 256 +
                                        (((2 * (c + 4) + hi) * 16) ^ ((lq & 15) << 4)));
            sa = __builtin_amdgcn_mfma_f32_32x32x16_f16(kfa, qf[c], sa, 0, 0, 0);
            sb = __builtin_amdgcn_mfma_f32_32x32x16_f16(kfb, qf[c + 4], sb, 0, 0, 0);
        }
        f32x16 sv = sa + sb;

        // K reads retired -> overwrite buffer with V tile (vmem path)
        asm volatile("s_waitcnt lgkmcnt(0)" ::: "memory");
        __builtin_amdgcn_sched_barrier(0);
        STAGE_V(k0)

        // ---- in-register online softmax (tree reductions; covers V latency) ----
        float red[8];
        #pragma unroll
        for (int r = 0; r < 8; ++r) red[r] = fmaxf(sv[2 * r], sv[2 * r + 1]);
        #pragma unroll
        for (int r = 0; r < 4; ++r) red[r] = fmaxf(red[r], red[r + 4]);
        red[0] = fmaxf(red[0], red[2]);
        red[1] = fmaxf(red[1], red[3]);
        float tm = fmaxf(red[0], red[1]);
        tm = fmaxf(tm, __shfl_xor(tm, 32));

        if (__any(tm > m + 8.f)) {           // defer-max (T13)
            float mnew = fmaxf(m, tm);
            float corr = __expf(m - mnew);
            m = mnew;
            lsum *= corr;
            #pragma unroll
            for (int dvt = 0; dvt < 4; ++dvt) o[dvt] *= corr;
        }
        #pragma unroll
        for (int r = 0; r < 16; ++r) sv[r] = __expf(sv[r] - m);
        float sr[8];
        #pragma unroll
        for (int r = 0; r < 8; ++r) sr[r] = sv[2 * r] + sv[2 * r + 1];
        #pragma unroll
        for (int r = 0; r < 4; ++r) sr[r] += sr[r + 4];
        sr[0] += sr[2]; sr[1] += sr[3];
        float ts = sr[0] + sr[1];
        ts += __shfl_xor(ts, 32);
        lsum += ts;

        int wv[8];
        #pragma unroll
        for (int i = 0; i < 8; ++i) wv[i] = pkrtz(sv[2 * i], sv[2 * i + 1]);

        asm volatile("s_waitcnt vmcnt(0)" ::: "memory");   // V tile landed
        __builtin_amdgcn_sched_barrier(0);

        // ---- O^T += V^T P : 2 k-slices x 4 dv-tiles ----
        #pragma unroll
        for (int s_ = 0; s_ < 2; ++s_) {
            const int base = s_ * 4;
            int x0 = __shfl_xor(wv[base + 0], 32);
            int x1 = __shfl_xor(wv[base + 1], 32);
            int x2 = __shfl_xor(wv[base + 2], 32);
            int x3 = __shfl_xor(wv[base + 3], 32);
            union { int i[4]; f16x8 v; } bu;
            bu.i[0] = hi ? x2 : wv[base + 0];
            bu.i[1] = hi ? x3 : wv[base + 1];
            bu.i[2] = hi ? wv[base + 2] : x0;
            bu.i[3] = hi ? wv[base + 3] : x1;
            #pragma unroll
            for (int dvt = 0; dvt < 4; ++dvt) {
                int rv = dvt * 32 + lq;
                f16x8 vf = *(const f16x8*)(KVw + rv * 64 +
                                           (((s_ * 2 + hi) ^ ((rv >> 1) & 3)) * 16));
                o[dvt] = __builtin_amdgcn_mfma_f32_32x32x16_f16(vf, bu.v, o[dvt], 0, 0, 0);
            }
        }

        // V reads retired -> stage next K tile
        asm volatile("s_waitcnt lgkmcnt(0)" ::: "memory");
        __builtin_amdgcn_sched_barrier(0);
        STAGE_K(knext)
    }
#undef STAGE_K
#undef STAGE_V
    asm volatile("s_waitcnt vmcnt(0)" ::: "memory");   // drain stray glls before LDS reuse

    // -------- 2-round tree merge of 4 wave partials (same 32 q-cols) --------
    float* obuf  = (float*)lds;                 // 2 snapshots x 4096 f32 = 32768 B
    float* mlbuf = (float*)(lds + 32768);       // 2 snapshots x 64 f32 = 512 B

    float lfin = 0.f;                            // valid in w==0 after final merge
    __syncthreads();
    if (w == 1 || w == 3) {
        int sb_ = (w == 3);
        #pragma unroll
        for (int dvt = 0; dvt < 4; ++dvt)
            #pragma unroll
            for (int r = 0; r < 16; ++r)
                obuf[sb_ * 4096 + (dvt * 16 + r) * 64 + l] = o[dvt][r];
        if (l < 32) {
            mlbuf[sb_ * 64 + l * 2 + 0] = m;
            mlbuf[sb_ * 64 + l * 2 + 1] = lsum;
        }
    }
    __syncthreads();
    if (w == 0 || w == 2) {
        int sb_ = (w == 2);
        float mo  = mlbuf[sb_ * 64 + lq * 2 + 0];
        float lo_ = mlbuf[sb_ * 64 + lq * 2 + 1];
        float mn = fmaxf(m, mo);
        float ca = __expf(m - mn);
        float cb = __expf(mo - mn);
        m = mn;
        lsum = lsum * ca + lo_ * cb;
        #pragma unroll
        for (int dvt = 0; dvt < 4; ++dvt)
            #pragma unroll
            for (int r = 0; r < 16; ++r)
                o[dvt][r] = o[dvt][r] * ca + obuf[sb_ * 4096 + (dvt * 16 + r) * 64 + l] * cb;
    }
    __syncthreads();
    if (w == 2) {
        #pragma unroll
        for (int dvt = 0; dvt < 4; ++dvt)
            #pragma unroll
            for (int r = 0; r < 16; ++r)
                obuf[(dvt * 16 + r) * 64 + l] = o[dvt][r];
        if (l < 32) {
            mlbuf[l * 2 + 0] = m;
            mlbuf[l * 2 + 1] = lsum;
        }
    }
    __syncthreads();
    if (w == 0) {
        float mo  = mlbuf[lq * 2 + 0];
        float lo_ = mlbuf[lq * 2 + 1];
        float mn = fmaxf(m, mo);
        float ca = __expf(m - mn);
        float cb = __expf(mo - mn);
        lfin = lsum * ca + lo_ * cb;
        float rl = 1.0f / lfin;
        #pragma unroll
        for (int dvt = 0; dvt < 4; ++dvt)
            #pragma unroll
            for (int r = 0; r < 16; ++r)
                o[dvt][r] = (o[dvt][r] * ca + obuf[(dvt * 16 + r) * 64 + l] * cb) * rl;
        if (nsplit == 2 && l < 32) {         // per-split stats for the combine pass
            int qg = b * SEQ + qt * 32 + lq;
            ml[(size_t)(s * 2 + 0) * NS + qg] = mn;
            ml[(size_t)(s * 2 + 1) * NS + qg] = lfin;
        }
    }
    __syncthreads();
    // -------- transpose O^T -> row-major via LDS, coalesced store --------
    float* tbuf = (float*)lds;                  // [32][132] f32
    if (w == 0) {
        #pragma unroll
        for (int dvt = 0; dvt < 4; ++dvt)
            #pragma unroll
            for (int r = 0; r < 16; ++r) {
                int dv = dvt * 32 + (r & 3) + 8 * (r >> 2) + 4 * hi;
                tbuf[lq * 132 + dv] = o[dvt][r];
            }
    }
    __syncthreads();
    const size_t obase = (size_t)(b * SEQ + qt * 32) * DKV;
    int row = t >> 3, c0 = (t & 7) * 16;
    if (s == 0) {                               // nsplit==1 also lands here
        #pragma unroll
        for (int i = 0; i < 4; ++i) {
            float4 v = *(const float4*)(tbuf + row * 132 + c0 + i * 4);
            *(float4*)(out + obase + row * 128 + c0 + i * 4) = v;
        }
    } else {
        #pragma unroll
        for (int i = 0; i < 4; ++i) {
            float4 v = *(const float4*)(tbuf + row * 132 + c0 + i * 4);
            f16x4 h = {(_Float16)v.x, (_Float16)v.y, (_Float16)v.z, (_Float16)v.w};
            *(f16x4*)(O1h + obase + row * 128 + c0 + i * 4) = h;
        }
    }
}

// ---------------- kernel 3: combine two split partials (r5-proven math) ----------------
__global__ __launch_bounds__(256) void combine_kernel(
    float* __restrict__ out, const _Float16* __restrict__ O1h,
    const float* __restrict__ ml) {
    int g = blockIdx.x * 256 + threadIdx.x;   // NS*32 threads, 4 cols each
    int r = g >> 5;
    int c0 = (g & 31) * 4;
    float m0 = ml[r],                  l0 = ml[(size_t)NS + r];
    float m1 = ml[(size_t)2 * NS + r], l1 = ml[(size_t)3 * NS + r];
    float M = fmaxf(m0, m1);
    float w0 = l0 * __expf(m0 - M);
    float w1 = l1 * __expf(m1 - M);
    float inv = 1.0f / (w0 + w1);
    float4 a = *(const float4*)(out + (size_t)r * DKV + c0);
    f16x4 h = *(const f16x4*)(O1h + (size_t)r * DKV + c0);
    float4 res;
    res.x = (w0 * a.x + w1 * (float)h[0]) * inv;
    res.y = (w0 * a.y + w1 * (float)h[1]) * inv;
    res.z = (w0 * a.z + w1 * (float)h[2]) * inv;
    res.w = (w0 * a.w + w1 * (float)h[3]) * inv;
    *(float4*)(out + (size_t)r * DKV + c0) = res;
}

extern "C" void kernel_launch(void* const* d_in, const int* in_sizes, int n_in,
                              void* d_out, int out_size, void* d_ws, size_t ws_size,
                              hipStream_t stream) {
    const float* X  = (const float*)d_in[0];
    const float* Wq = (const float*)d_in[1];
    const float* bq = (const float*)d_in[2];
    const float* Wk = (const float*)d_in[3];
    const float* bk = (const float*)d_in[4];
    const float* Wv = (const float*)d_in[5];
    const float* bv = (const float*)d_in[6];
    float* out = (float*)d_out;

    const size_t nqe = (size_t)NB * SEQ * DKV;            // 2M elements
    _Float16* Qh  = (_Float16*)d_ws;
    _Float16* Kh  = Qh  + nqe;
    _Float16* VTh = Kh  + nqe;
    _Float16* WTh = VTh + nqe;                            // 3*128*1024 f16
    size_t f16_bytes = (3 * nqe + (size_t)3 * 128 * 1024) * sizeof(_Float16);
    f16_bytes = (f16_bytes + 255) & ~(size_t)255;

    size_t o1_bytes = nqe * sizeof(_Float16);             // 4.2 MB
    size_t ml_bytes = (size_t)4 * NS * sizeof(float);     // 0.26 MB
    int nsplit = (ws_size >= f16_bytes + o1_bytes + ml_bytes) ? 2 : 1;
    int kps = SEQ / nsplit;

    _Float16* O1h = (_Float16*)((char*)d_ws + f16_bytes);
    float* ml = (float*)((char*)d_ws + f16_bytes + o1_bytes);

    prep_wt<<<(3 * 1024 * 128) / 256, 256, 0, stream>>>(Wq, Wk, Wv, WTh);
    qkv_proj<<<(NB * SEQ / 64) * 3, 256, 0, stream>>>(X, bq, bk, bv, WTh, Qh, Kh, VTh);
    attn_kernel<<<NB * 128 * nsplit, 256, 0, stream>>>(Qh, Kh, VTh, out, O1h, ml,
                                                       nsplit, kps);
    if (nsplit == 2)
        combine_kernel<<<(NS * 32) / 256, 256, 0, stream>>>(out, O1h, ml);
}

// Round 19
// 119.390 us; speedup vs baseline: 1.0257x; 1.0257x over previous
//
#include <hip/hip_runtime.h>

#define NB 4
#define SEQ 4096
#define DIMK 1024
#define DKV 128
#define SCALE 0.08838834764831845f      // 1/sqrt(128)
#define QSCALE 0.1275174272f            // SCALE*log2(e): softmax in exp2 domain (r13-proven)

typedef float  f32x4  __attribute__((ext_vector_type(4)));
typedef float  f32x16 __attribute__((ext_vector_type(16)));
typedef _Float16 f16x8 __attribute__((ext_vector_type(8)));

static __device__ __forceinline__ int pkrtz(float a, float b) {
    auto h = __builtin_amdgcn_cvt_pkrtz(a, b);   // __fp16 ext_vector(2)
    return __builtin_bit_cast(int, h);
}

// async global->LDS, 16B per lane; LDS dest = wave-uniform base + lane*16 (linear)
static __device__ __forceinline__ void gll16(const void* g, void* l) {
    __builtin_amdgcn_global_load_lds((const __attribute__((address_space(1))) char*)g,
                                     (__attribute__((address_space(3))) char*)l, 16, 0, 0);
}

// ---------------- kernel 0: transpose W -> f16 WT[3][128][1024] ----------------
__global__ void prep_wt(const float* __restrict__ Wq, const float* __restrict__ Wk,
                        const float* __restrict__ Wv, _Float16* __restrict__ WT) {
    int tid = blockIdx.x * 256 + threadIdx.x;
    int n  = tid & 127;
    int k  = (tid >> 7) & 1023;
    int w3 = tid >> 17;
    const float* W = (w3 == 0) ? Wq : (w3 == 1) ? Wk : Wv;
    WT[((size_t)w3 * 128 + n) * 1024 + k] = (_Float16)W[(size_t)k * 128 + n];
}

// ---------------- kernel 1: QKV projection + XCD sibling swizzle (r18-proven, ~-8us) ----------------
__global__ __launch_bounds__(256, 2) void qkv_proj(
    const float* __restrict__ X,
    const float* __restrict__ bq, const float* __restrict__ bk, const float* __restrict__ bv,
    const _Float16* __restrict__ WT,
    _Float16* __restrict__ Qh, _Float16* __restrict__ Kh, _Float16* __restrict__ VTh) {

    __shared__ __attribute__((aligned(16))) char WTs[2][128 * 144];   // 36864 B
    const int t = threadIdx.x;
    const int w = t >> 6, l = t & 63;
    const int lrow = l & 15, lg = l >> 4;
    const int work = (blockIdx.x & 7) * 96 + (blockIdx.x >> 3);   // grid 768 = 8 x 96
    const int w3   = work % 3;
    const int tile = work / 3;
    const int r0 = tile * 64;

    f32x4 acc[8] = {};
    const float* xrow = X + (size_t)(r0 + w * 16 + lrow) * DIMK;
    const _Float16* Wbase = WT + (size_t)w3 * 128 * 1024;

    const int srow = t >> 3, spart = t & 7;        // + 32 rows per chunk index

    {
        int4 wreg[4];
        #pragma unroll
        for (int i = 0; i < 4; ++i)
            wreg[i] = *(const int4*)(Wbase + (size_t)(srow + 32 * i) * 1024 + spart * 8);
        #pragma unroll
        for (int i = 0; i < 4; ++i)
            *(int4*)(WTs[0] + (srow + 32 * i) * 144 + spart * 16) = wreg[i];
    }
    float4 xc0 = *(const float4*)(xrow + lg * 8);
    float4 xc1 = *(const float4*)(xrow + lg * 8 + 4);
    float4 xc2 = *(const float4*)(xrow + 32 + lg * 8);
    float4 xc3 = *(const float4*)(xrow + 32 + lg * 8 + 4);
    __syncthreads();

    for (int kt = 0; kt < 16; ++kt) {
        const int cur = kt & 1;
        const int k0n = ((kt + 1) & 15) * 64;      // wrap: last-iter data unused
        float4 xn0 = *(const float4*)(xrow + k0n + lg * 8);
        float4 xn1 = *(const float4*)(xrow + k0n + lg * 8 + 4);
        float4 xn2 = *(const float4*)(xrow + k0n + 32 + lg * 8);
        float4 xn3 = *(const float4*)(xrow + k0n + 32 + lg * 8 + 4);
        int4 wreg[4];
        #pragma unroll
        for (int i = 0; i < 4; ++i)
            wreg[i] = *(const int4*)(Wbase + (size_t)(srow + 32 * i) * 1024 + k0n + spart * 8);

        #pragma unroll
        for (int kk = 0; kk < 2; ++kk) {
            f16x8 a;
            float4 u = kk ? xc2 : xc0, v = kk ? xc3 : xc1;
            a[0] = (_Float16)u.x; a[1] = (_Float16)u.y; a[2] = (_Float16)u.z; a[3] = (_Float16)u.w;
            a[4] = (_Float16)v.x; a[5] = (_Float16)v.y; a[6] = (_Float16)v.z; a[7] = (_Float16)v.w;
            #pragma unroll
            for (int n = 0; n < 8; ++n) {
                f16x8 bf = *(const f16x8*)(WTs[cur] + (n * 16 + lrow) * 144 +
                                           kk * 64 + lg * 16);
                acc[n] = __builtin_amdgcn_mfma_f32_16x16x32_f16(a, bf, acc[n], 0, 0, 0);
            }
        }
        #pragma unroll
        for (int i = 0; i < 4; ++i)
            *(int4*)(WTs[cur ^ 1] + (srow + 32 * i) * 144 + spart * 16) = wreg[i];
        __syncthreads();
        xc0 = xn0; xc1 = xn1; xc2 = xn2; xc3 = xn3;
    }

    const float* bias = (w3 == 0) ? bq : (w3 == 1) ? bk : bv;
    #pragma unroll
    for (int n = 0; n < 8; ++n) {
        int col = n * 16 + lrow;
        float bv_ = bias[col];
        #pragma unroll
        for (int j = 0; j < 4; ++j) {
            int grow = r0 + w * 16 + lg * 4 + j;
            float val = acc[n][j] + bv_;
            if (w3 == 0) {
                Qh[(size_t)grow * DKV + col] = (_Float16)(val * QSCALE);
            } else if (w3 == 1) {
                Kh[(size_t)grow * DKV + col] = (_Float16)val;
            } else {
                int b = grow >> 12, sp = grow & 4095;
                VTh[((size_t)b * DKV + col) * SEQ + sp] = (_Float16)val;
            }
        }
    }
}

// ---------------- kernel 2: flash attention (r17 best structure + exp2 domain) ----------------
// grid 512 (XCD-swizzled), 256 thr = 4 waves, wave-private 1024 keys, KVBLK=32,
// dual K/V LDS buffers staged via global_load_lds (vmem path, no ds_writes).
// Ordering: vmcnt(0)[tile t] -> QK^T -> lgkm(0) -> K-gll(t+1) -> softmax(exp2)
//           -> PV -> lgkm(0) -> V-gll(t+1).
// exp2 domain (QSCALE folded at projection): deletes 16 v_mul/iter from the
// VALU pipe (the largest consumer, 30%).
__global__ __launch_bounds__(256, 2) void attn_kernel(
    const _Float16* __restrict__ Qh, const _Float16* __restrict__ Kh,
    const _Float16* __restrict__ VTh, float* __restrict__ out) {

    __shared__ __attribute__((aligned(16))) char lds[65536];

    const int t = threadIdx.x;
    const int w = t >> 6, l = t & 63;
    const int lq = l & 31;          // q column within tile
    const int hi = l >> 5;

    // XCD-chunked swizzle over 512 blocks
    const int work = (blockIdx.x & 7) * 64 + (blockIdx.x >> 3);
    const int b  = work >> 7;            // 128 q-tiles per batch
    const int qt = work & 127;
    const int q0 = qt * 32;

    char* Kw = lds + w * 16384;          // [32 k][128 dk] f16: LDS[r][x]=K[r][x^(r&15)]
    char* Vw = Kw + 8192;                // [128 dv][32 k] f16: chunk-XOR (dv>>1)&3

    f16x8 qf[8];
    #pragma unroll
    for (int c = 0; c < 8; ++c)
        qf[c] = *(const f16x8*)(Qh + (size_t)(b * SEQ + q0 + lq) * DKV + c * 16 + hi * 8);

    f32x16 o[4] = {};                    // O^T: 4 dv-tiles of 32, q = lq
    float m = -INFINITY, lsum = 0.f;

    const _Float16* Kbase = Kh + (size_t)(b * SEQ + w * 1024) * DKV;
    const _Float16* Vbase = VTh + (size_t)b * DKV * SEQ + w * 1024;

    const int krow_ = l >> 4;                       // + 4 per K-chunk
    const int vdv_  = l >> 2;                       // + 16 per V-chunk

#define STAGE_K(KOFF) {                                                                   \
        _Pragma("unroll")                                                                 \
        for (int i = 0; i < 8; ++i) {                                                     \
            int row = 4 * i + krow_;                                                      \
            int part = (l & 15) ^ (row & 15);                                             \
            gll16(Kbase + (size_t)((KOFF) + row) * DKV + part * 8, Kw + i * 1024);        \
        }                                                                                 \
    }
#define STAGE_V(KOFF) {                                                                   \
        _Pragma("unroll")                                                                 \
        for (int i = 0; i < 8; ++i) {                                                     \
            int dv = 16 * i + vdv_;                                                       \
            int p = (l & 3) ^ ((dv >> 1) & 3);                                            \
            gll16(Vbase + (size_t)dv * SEQ + (KOFF) + p * 8, Vw + i * 1024);              \
        }                                                                                 \
    }

    // ---- prologue: stage tile 0 ----
    STAGE_K(0)
    STAGE_V(0)

    for (int kt = 0; kt < 32; ++kt) {
        const int kn = ((kt + 1) & 31) * 32;       // next tile offset (wrap: unused data)

        asm volatile("s_waitcnt vmcnt(0)" ::: "memory");   // tile kt fully in LDS
        __builtin_amdgcn_sched_barrier(0);

        // ---- S^T = K Q^T : two independent 4-deep MFMA chains ----
        f32x16 sa = {}, sb = {};
        #pragma unroll
        for (int c = 0; c < 4; ++c) {
            f16x8 kfa = *(const f16x8*)(Kw + lq * 256 +
                                        (((2 * c + hi) * 16) ^ ((lq & 15) << 4)));
            f16x8 kfb = *(const f16x8*)(Kw + lq * 256 +
                                        (((2 * (c + 4) + hi) * 16) ^ ((lq & 15) << 4)));
            sa = __builtin_amdgcn_mfma_f32_32x32x16_f16(kfa, qf[c], sa, 0, 0, 0);
            sb = __builtin_amdgcn_mfma_f32_32x32x16_f16(kfb, qf[c + 4], sb, 0, 0, 0);
        }
        f32x16 s = sa + sb;

        // K reads retired -> safe to overwrite K region with next tile
        asm volatile("s_waitcnt lgkmcnt(0)" ::: "memory");
        __builtin_amdgcn_sched_barrier(0);
        STAGE_K(kn)

        // ---- in-register online softmax (exp2 domain, tree reductions) ----
        float red[8];
        #pragma unroll
        for (int r = 0; r < 8; ++r) red[r] = fmaxf(s[2 * r], s[2 * r + 1]);
        #pragma unroll
        for (int r = 0; r < 4; ++r) red[r] = fmaxf(red[r], red[r + 4]);
        red[0] = fmaxf(red[0], red[2]);
        red[1] = fmaxf(red[1], red[3]);
        float tm = fmaxf(red[0], red[1]);
        tm = fmaxf(tm, __shfl_xor(tm, 32));

        if (__any(tm > m + 8.f)) {           // defer-max (T13)
            float mnew = fmaxf(m, tm);
            float corr = exp2f(m - mnew);
            m = mnew;
            lsum *= corr;
            #pragma unroll
            for (int dvt = 0; dvt < 4; ++dvt) o[dvt] *= corr;
        }
        #pragma unroll
        for (int r = 0; r < 16; ++r) s[r] = exp2f(s[r] - m);
        float sr[8];
        #pragma unroll
        for (int r = 0; r < 8; ++r) sr[r] = s[2 * r] + s[2 * r + 1];
        #pragma unroll
        for (int r = 0; r < 4; ++r) sr[r] += sr[r + 4];
        sr[0] += sr[2]; sr[1] += sr[3];
        float ts = sr[0] + sr[1];
        ts += __shfl_xor(ts, 32);
        lsum += ts;

        // pack P to f16 (T12)
        int wv[8];
        #pragma unroll
        for (int i = 0; i < 8; ++i) wv[i] = pkrtz(s[2 * i], s[2 * i + 1]);

        // ---- O^T += V^T P : 2 k-slices x 4 dv-tiles (V from LDS) ----
        #pragma unroll
        for (int s_ = 0; s_ < 2; ++s_) {
            const int base = s_ * 4;
            int x0 = __shfl_xor(wv[base + 0], 32);
            int x1 = __shfl_xor(wv[base + 1], 32);
            int x2 = __shfl_xor(wv[base + 2], 32);
            int x3 = __shfl_xor(wv[base + 3], 32);
            union { int i[4]; f16x8 v; } bu;
            bu.i[0] = hi ? x2 : wv[base + 0];
            bu.i[1] = hi ? x3 : wv[base + 1];
            bu.i[2] = hi ? wv[base + 2] : x0;
            bu.i[3] = hi ? wv[base + 3] : x1;
            #pragma unroll
            for (int dvt = 0; dvt < 4; ++dvt) {
                int rv = dvt * 32 + lq;
                f16x8 vf = *(const f16x8*)(Vw + rv * 64 +
                                           (((s_ * 2 + hi) ^ ((rv >> 1) & 3)) * 16));
                o[dvt] = __builtin_amdgcn_mfma_f32_32x32x16_f16(vf, bu.v, o[dvt], 0, 0, 0);
            }
        }

        // V reads retired -> stage next V tile
        asm volatile("s_waitcnt lgkmcnt(0)" ::: "memory");
        __builtin_amdgcn_sched_barrier(0);
        STAGE_V(kn)
    }
#undef STAGE_K
#undef STAGE_V
    asm volatile("s_waitcnt vmcnt(0)" ::: "memory");   // drain stray glls before LDS reuse

    // -------- 2-round tree merge of 4 wave partials (same 32 q-cols) --------
    float* obuf  = (float*)lds;                 // 2 snapshots x 4096 f32 = 32 KB
    float* mlbuf = (float*)(lds + 49152);       // 2 snapshots x 64 f32

    __syncthreads();
    if (w == 1 || w == 3) {
        int sb_ = (w == 3);
        #pragma unroll
        for (int dvt = 0; dvt < 4; ++dvt)
            #pragma unroll
            for (int r = 0; r < 16; ++r)
                obuf[sb_ * 4096 + (dvt * 16 + r) * 64 + l] = o[dvt][r];
        if (l < 32) {
            mlbuf[sb_ * 64 + l * 2 + 0] = m;
            mlbuf[sb_ * 64 + l * 2 + 1] = lsum;
        }
    }
    __syncthreads();
    if (w == 0 || w == 2) {
        int sb_ = (w == 2);
        float mo  = mlbuf[sb_ * 64 + lq * 2 + 0];
        float lo_ = mlbuf[sb_ * 64 + lq * 2 + 1];
        float mn = fmaxf(m, mo);
        float ca = exp2f(m - mn);
        float cb = exp2f(mo - mn);
        m = mn;
        lsum = lsum * ca + lo_ * cb;
        #pragma unroll
        for (int dvt = 0; dvt < 4; ++dvt)
            #pragma unroll
            for (int r = 0; r < 16; ++r)
                o[dvt][r] = o[dvt][r] * ca + obuf[sb_ * 4096 + (dvt * 16 + r) * 64 + l] * cb;
    }
    __syncthreads();
    if (w == 2) {
        #pragma unroll
        for (int dvt = 0; dvt < 4; ++dvt)
            #pragma unroll
            for (int r = 0; r < 16; ++r)
                obuf[(dvt * 16 + r) * 64 + l] = o[dvt][r];
        if (l < 32) {
            mlbuf[l * 2 + 0] = m;
            mlbuf[l * 2 + 1] = lsum;
        }
    }
    __syncthreads();
    if (w == 0) {
        float mo  = mlbuf[lq * 2 + 0];
        float lo_ = mlbuf[lq * 2 + 1];
        float mn = fmaxf(m, mo);
        float ca = exp2f(m - mn);
        float cb = exp2f(mo - mn);
        float rl = 1.0f / (lsum * ca + lo_ * cb);
        #pragma unroll
        for (int dvt = 0; dvt < 4; ++dvt)
            #pragma unroll
            for (int r = 0; r < 16; ++r)
                o[dvt][r] = (o[dvt][r] * ca + obuf[(dvt * 16 + r) * 64 + l] * cb) * rl;
    }
    __syncthreads();
    // -------- transpose O^T -> row-major via LDS, coalesced store --------
    float* tbuf = (float*)lds;                  // [32][132] f32
    if (w == 0) {
        #pragma unroll
        for (int dvt = 0; dvt < 4; ++dvt)
            #pragma unroll
            for (int r = 0; r < 16; ++r) {
                int dv = dvt * 32 + (r & 3) + 8 * (r >> 2) + 4 * hi;
                tbuf[lq * 132 + dv] = o[dvt][r];
            }
    }
    __syncthreads();
    const size_t obase = (size_t)(b * SEQ + qt * 32) * DKV;
    int row = t >> 3, c0 = (t & 7) * 16;
    #pragma unroll
    for (int i = 0; i < 4; ++i) {
        float4 v = *(const float4*)(tbuf + row * 132 + c0 + i * 4);
        *(float4*)(out + obase + row * 128 + c0 + i * 4) = v;
    }
}

extern "C" void kernel_launch(void* const* d_in, const int* in_sizes, int n_in,
                              void* d_out, int out_size, void* d_ws, size_t ws_size,
                              hipStream_t stream) {
    const float* X  = (const float*)d_in[0];
    const float* Wq = (const float*)d_in[1];
    const float* bq = (const float*)d_in[2];
    const float* Wk = (const float*)d_in[3];
    const float* bk = (const float*)d_in[4];
    const float* Wv = (const float*)d_in[5];
    const float* bv = (const float*)d_in[6];
    float* out = (float*)d_out;

    const size_t nqe = (size_t)NB * SEQ * DKV;            // 2M elements
    _Float16* Qh  = (_Float16*)d_ws;
    _Float16* Kh  = Qh  + nqe;
    _Float16* VTh = Kh  + nqe;
    _Float16* WTh = VTh + nqe;                            // 3*128*1024 f16

    prep_wt<<<(3 * 1024 * 128) / 256, 256, 0, stream>>>(Wq, Wk, Wv, WTh);
    qkv_proj<<<(NB * SEQ / 64) * 3, 256, 0, stream>>>(X, bq, bk, bv, WTh, Qh, Kh, VTh);
    attn_kernel<<<NB * 128, 256, 0, stream>>>(Qh, Kh, VTh, out);
}

// Round 20
// 116.200 us; speedup vs baseline: 1.0539x; 1.0274x over previous
//
#include <hip/hip_runtime.h>

#define NB 4
#define SEQ 4096
#define DIMK 1024
#define DKV 128
#define SCALE 0.08838834764831845f   // 1/sqrt(128)

typedef float  f32x4  __attribute__((ext_vector_type(4)));
typedef float  f32x16 __attribute__((ext_vector_type(16)));
typedef _Float16 f16x8 __attribute__((ext_vector_type(8)));

static __device__ __forceinline__ int pkrtz(float a, float b) {
    auto h = __builtin_amdgcn_cvt_pkrtz(a, b);   // __fp16 ext_vector(2)
    return __builtin_bit_cast(int, h);
}

// async global->LDS, 16B per lane; LDS dest = wave-uniform base + lane*16 (linear)
static __device__ __forceinline__ void gll16(const void* g, void* l) {
    __builtin_amdgcn_global_load_lds((const __attribute__((address_space(1))) char*)g,
                                     (__attribute__((address_space(3))) char*)l, 16, 0, 0);
}

// ---------------- kernel 0: transpose W -> f16 WT[3][128][1024] ----------------
__global__ void prep_wt(const float* __restrict__ Wq, const float* __restrict__ Wk,
                        const float* __restrict__ Wv, _Float16* __restrict__ WT) {
    int tid = blockIdx.x * 256 + threadIdx.x;
    int n  = tid & 127;
    int k  = (tid >> 7) & 1023;
    int w3 = tid >> 17;
    const float* W = (w3 == 0) ? Wq : (w3 == 1) ? Wk : Wv;
    WT[((size_t)w3 * 128 + n) * 1024 + k] = (_Float16)W[(size_t)k * 128 + n];
}

// ---------------- kernel 1: QKV projection + XCD sibling swizzle (r18/r19-proven) ----------------
__global__ __launch_bounds__(256, 2) void qkv_proj(
    const float* __restrict__ X,
    const float* __restrict__ bq, const float* __restrict__ bk, const float* __restrict__ bv,
    const _Float16* __restrict__ WT,
    _Float16* __restrict__ Qh, _Float16* __restrict__ Kh, _Float16* __restrict__ VTh) {

    __shared__ __attribute__((aligned(16))) char WTs[2][128 * 144];   // 36864 B
    const int t = threadIdx.x;
    const int w = t >> 6, l = t & 63;
    const int lrow = l & 15, lg = l >> 4;
    const int work = (blockIdx.x & 7) * 96 + (blockIdx.x >> 3);   // grid 768 = 8 x 96
    const int w3   = work % 3;
    const int tile = work / 3;
    const int r0 = tile * 64;

    f32x4 acc[8] = {};
    const float* xrow = X + (size_t)(r0 + w * 16 + lrow) * DIMK;
    const _Float16* Wbase = WT + (size_t)w3 * 128 * 1024;

    const int srow = t >> 3, spart = t & 7;        // + 32 rows per chunk index

    {
        int4 wreg[4];
        #pragma unroll
        for (int i = 0; i < 4; ++i)
            wreg[i] = *(const int4*)(Wbase + (size_t)(srow + 32 * i) * 1024 + spart * 8);
        #pragma unroll
        for (int i = 0; i < 4; ++i)
            *(int4*)(WTs[0] + (srow + 32 * i) * 144 + spart * 16) = wreg[i];
    }
    float4 xc0 = *(const float4*)(xrow + lg * 8);
    float4 xc1 = *(const float4*)(xrow + lg * 8 + 4);
    float4 xc2 = *(const float4*)(xrow + 32 + lg * 8);
    float4 xc3 = *(const float4*)(xrow + 32 + lg * 8 + 4);
    __syncthreads();

    for (int kt = 0; kt < 16; ++kt) {
        const int cur = kt & 1;
        const int k0n = ((kt + 1) & 15) * 64;      // wrap: last-iter data unused
        float4 xn0 = *(const float4*)(xrow + k0n + lg * 8);
        float4 xn1 = *(const float4*)(xrow + k0n + lg * 8 + 4);
        float4 xn2 = *(const float4*)(xrow + k0n + 32 + lg * 8);
        float4 xn3 = *(const float4*)(xrow + k0n + 32 + lg * 8 + 4);
        int4 wreg[4];
        #pragma unroll
        for (int i = 0; i < 4; ++i)
            wreg[i] = *(const int4*)(Wbase + (size_t)(srow + 32 * i) * 1024 + k0n + spart * 8);

        #pragma unroll
        for (int kk = 0; kk < 2; ++kk) {
            f16x8 a;
            float4 u = kk ? xc2 : xc0, v = kk ? xc3 : xc1;
            a[0] = (_Float16)u.x; a[1] = (_Float16)u.y; a[2] = (_Float16)u.z; a[3] = (_Float16)u.w;
            a[4] = (_Float16)v.x; a[5] = (_Float16)v.y; a[6] = (_Float16)v.z; a[7] = (_Float16)v.w;
            #pragma unroll
            for (int n = 0; n < 8; ++n) {
                f16x8 bf = *(const f16x8*)(WTs[cur] + (n * 16 + lrow) * 144 +
                                           kk * 64 + lg * 16);
                acc[n] = __builtin_amdgcn_mfma_f32_16x16x32_f16(a, bf, acc[n], 0, 0, 0);
            }
        }
        #pragma unroll
        for (int i = 0; i < 4; ++i)
            *(int4*)(WTs[cur ^ 1] + (srow + 32 * i) * 144 + spart * 16) = wreg[i];
        __syncthreads();
        xc0 = xn0; xc1 = xn1; xc2 = xn2; xc3 = xn3;
    }

    const float* bias = (w3 == 0) ? bq : (w3 == 1) ? bk : bv;
    #pragma unroll
    for (int n = 0; n < 8; ++n) {
        int col = n * 16 + lrow;
        float bv_ = bias[col];
        #pragma unroll
        for (int j = 0; j < 4; ++j) {
            int grow = r0 + w * 16 + lg * 4 + j;
            float val = acc[n][j] + bv_;
            if (w3 == 0) {
                Qh[(size_t)grow * DKV + col] = (_Float16)(val * SCALE);
            } else if (w3 == 1) {
                Kh[(size_t)grow * DKV + col] = (_Float16)val;
            } else {
                int b = grow >> 12, sp = grow & 4095;
                VTh[((size_t)b * DKV + col) * SEQ + sp] = (_Float16)val;
            }
        }
    }
}

// ---------------- kernel 2: flash attention (r17 structure + T5 setprio) ----------------
// r19 lesson: exp2f = precise OCML path, slower than __expf intrinsic -> reverted.
// Single new delta vs r17: s_setprio(1) around both MFMA clusters. Mechanism: no
// main-loop barriers -> 8 waves/CU free-run at different phases; scheduler can favor
// MFMA-entering waves (m191: +4-7% attn in exactly this regime; null only lockstep).
__global__ __launch_bounds__(256, 2) void attn_kernel(
    const _Float16* __restrict__ Qh, const _Float16* __restrict__ Kh,
    const _Float16* __restrict__ VTh, float* __restrict__ out) {

    __shared__ __attribute__((aligned(16))) char lds[65536];

    const int t = threadIdx.x;
    const int w = t >> 6, l = t & 63;
    const int lq = l & 31;          // q column within tile
    const int hi = l >> 5;

    // XCD-chunked swizzle over 512 blocks
    const int work = (blockIdx.x & 7) * 64 + (blockIdx.x >> 3);
    const int b  = work >> 7;            // 128 q-tiles per batch
    const int qt = work & 127;
    const int q0 = qt * 32;

    char* Kw = lds + w * 16384;          // [32 k][128 dk] f16: LDS[r][x]=K[r][x^(r&15)]
    char* Vw = Kw + 8192;                // [128 dv][32 k] f16: chunk-XOR (dv>>1)&3

    f16x8 qf[8];
    #pragma unroll
    for (int c = 0; c < 8; ++c)
        qf[c] = *(const f16x8*)(Qh + (size_t)(b * SEQ + q0 + lq) * DKV + c * 16 + hi * 8);

    f32x16 o[4] = {};                    // O^T: 4 dv-tiles of 32, q = lq
    float m = -INFINITY, lsum = 0.f;

    const _Float16* Kbase = Kh + (size_t)(b * SEQ + w * 1024) * DKV;
    const _Float16* Vbase = VTh + (size_t)b * DKV * SEQ + w * 1024;

    const int krow_ = l >> 4;                       // + 4 per K-chunk
    const int vdv_  = l >> 2;                       // + 16 per V-chunk

#define STAGE_K(KOFF) {                                                                   \
        _Pragma("unroll")                                                                 \
        for (int i = 0; i < 8; ++i) {                                                     \
            int row = 4 * i + krow_;                                                      \
            int part = (l & 15) ^ (row & 15);                                             \
            gll16(Kbase + (size_t)((KOFF) + row) * DKV + part * 8, Kw + i * 1024);        \
        }                                                                                 \
    }
#define STAGE_V(KOFF) {                                                                   \
        _Pragma("unroll")                                                                 \
        for (int i = 0; i < 8; ++i) {                                                     \
            int dv = 16 * i + vdv_;                                                       \
            int p = (l & 3) ^ ((dv >> 1) & 3);                                            \
            gll16(Vbase + (size_t)dv * SEQ + (KOFF) + p * 8, Vw + i * 1024);              \
        }                                                                                 \
    }

    // ---- prologue: stage tile 0 ----
    STAGE_K(0)
    STAGE_V(0)

    for (int kt = 0; kt < 32; ++kt) {
        const int kn = ((kt + 1) & 31) * 32;       // next tile offset (wrap: unused data)

        asm volatile("s_waitcnt vmcnt(0)" ::: "memory");   // tile kt fully in LDS
        __builtin_amdgcn_sched_barrier(0);

        // ---- S^T = K Q^T : two independent 4-deep MFMA chains ----
        f32x16 sa = {}, sb = {};
        __builtin_amdgcn_s_setprio(1);
        #pragma unroll
        for (int c = 0; c < 4; ++c) {
            f16x8 kfa = *(const f16x8*)(Kw + lq * 256 +
                                        (((2 * c + hi) * 16) ^ ((lq & 15) << 4)));
            f16x8 kfb = *(const f16x8*)(Kw + lq * 256 +
                                        (((2 * (c + 4) + hi) * 16) ^ ((lq & 15) << 4)));
            sa = __builtin_amdgcn_mfma_f32_32x32x16_f16(kfa, qf[c], sa, 0, 0, 0);
            sb = __builtin_amdgcn_mfma_f32_32x32x16_f16(kfb, qf[c + 4], sb, 0, 0, 0);
        }
        __builtin_amdgcn_s_setprio(0);
        f32x16 s = sa + sb;

        // K reads retired -> safe to overwrite K region with next tile
        asm volatile("s_waitcnt lgkmcnt(0)" ::: "memory");
        __builtin_amdgcn_sched_barrier(0);
        STAGE_K(kn)

        // ---- in-register online softmax (tree reductions) ----
        float red[8];
        #pragma unroll
        for (int r = 0; r < 8; ++r) red[r] = fmaxf(s[2 * r], s[2 * r + 1]);
        #pragma unroll
        for (int r = 0; r < 4; ++r) red[r] = fmaxf(red[r], red[r + 4]);
        red[0] = fmaxf(red[0], red[2]);
        red[1] = fmaxf(red[1], red[3]);
        float tm = fmaxf(red[0], red[1]);
        tm = fmaxf(tm, __shfl_xor(tm, 32));

        if (__any(tm > m + 8.f)) {           // defer-max (T13)
            float mnew = fmaxf(m, tm);
            float corr = __expf(m - mnew);
            m = mnew;
            lsum *= corr;
            #pragma unroll
            for (int dvt = 0; dvt < 4; ++dvt) o[dvt] *= corr;
        }
        #pragma unroll
        for (int r = 0; r < 16; ++r) s[r] = __expf(s[r] - m);
        float sr[8];
        #pragma unroll
        for (int r = 0; r < 8; ++r) sr[r] = s[2 * r] + s[2 * r + 1];
        #pragma unroll
        for (int r = 0; r < 4; ++r) sr[r] += sr[r + 4];
        sr[0] += sr[2]; sr[1] += sr[3];
        float ts = sr[0] + sr[1];
        ts += __shfl_xor(ts, 32);
        lsum += ts;

        // pack P to f16 (T12)
        int wv[8];
        #pragma unroll
        for (int i = 0; i < 8; ++i) wv[i] = pkrtz(s[2 * i], s[2 * i + 1]);

        // ---- O^T += V^T P : 2 k-slices x 4 dv-tiles (V from LDS) ----
        #pragma unroll
        for (int s_ = 0; s_ < 2; ++s_) {
            const int base = s_ * 4;
            int x0 = __shfl_xor(wv[base + 0], 32);
            int x1 = __shfl_xor(wv[base + 1], 32);
            int x2 = __shfl_xor(wv[base + 2], 32);
            int x3 = __shfl_xor(wv[base + 3], 32);
            union { int i[4]; f16x8 v; } bu;
            bu.i[0] = hi ? x2 : wv[base + 0];
            bu.i[1] = hi ? x3 : wv[base + 1];
            bu.i[2] = hi ? wv[base + 2] : x0;
            bu.i[3] = hi ? wv[base + 3] : x1;
            __builtin_amdgcn_s_setprio(1);
            #pragma unroll
            for (int dvt = 0; dvt < 4; ++dvt) {
                int rv = dvt * 32 + lq;
                f16x8 vf = *(const f16x8*)(Vw + rv * 64 +
                                           (((s_ * 2 + hi) ^ ((rv >> 1) & 3)) * 16));
                o[dvt] = __builtin_amdgcn_mfma_f32_32x32x16_f16(vf, bu.v, o[dvt], 0, 0, 0);
            }
            __builtin_amdgcn_s_setprio(0);
        }

        // V reads retired -> stage next V tile
        asm volatile("s_waitcnt lgkmcnt(0)" ::: "memory");
        __builtin_amdgcn_sched_barrier(0);
        STAGE_V(kn)
    }
#undef STAGE_K
#undef STAGE_V
    asm volatile("s_waitcnt vmcnt(0)" ::: "memory");   // drain stray glls before LDS reuse

    // -------- 2-round tree merge of 4 wave partials (same 32 q-cols) --------
    float* obuf  = (float*)lds;                 // 2 snapshots x 4096 f32 = 32 KB
    float* mlbuf = (float*)(lds + 49152);       // 2 snapshots x 64 f32

    __syncthreads();
    if (w == 1 || w == 3) {
        int sb_ = (w == 3);
        #pragma unroll
        for (int dvt = 0; dvt < 4; ++dvt)
            #pragma unroll
            for (int r = 0; r < 16; ++r)
                obuf[sb_ * 4096 + (dvt * 16 + r) * 64 + l] = o[dvt][r];
        if (l < 32) {
            mlbuf[sb_ * 64 + l * 2 + 0] = m;
            mlbuf[sb_ * 64 + l * 2 + 1] = lsum;
        }
    }
    __syncthreads();
    if (w == 0 || w == 2) {
        int sb_ = (w == 2);
        float mo  = mlbuf[sb_ * 64 + lq * 2 + 0];
        float lo_ = mlbuf[sb_ * 64 + lq * 2 + 1];
        float mn = fmaxf(m, mo);
        float ca = __expf(m - mn);
        float cb = __expf(mo - mn);
        m = mn;
        lsum = lsum * ca + lo_ * cb;
        #pragma unroll
        for (int dvt = 0; dvt < 4; ++dvt)
            #pragma unroll
            for (int r = 0; r < 16; ++r)
                o[dvt][r] = o[dvt][r] * ca + obuf[sb_ * 4096 + (dvt * 16 + r) * 64 + l] * cb;
    }
    __syncthreads();
    if (w == 2) {
        #pragma unroll
        for (int dvt = 0; dvt < 4; ++dvt)
            #pragma unroll
            for (int r = 0; r < 16; ++r)
                obuf[(dvt * 16 + r) * 64 + l] = o[dvt][r];
        if (l < 32) {
            mlbuf[l * 2 + 0] = m;
            mlbuf[l * 2 + 1] = lsum;
        }
    }
    __syncthreads();
    if (w == 0) {
        float mo  = mlbuf[lq * 2 + 0];
        float lo_ = mlbuf[lq * 2 + 1];
        float mn = fmaxf(m, mo);
        float ca = __expf(m - mn);
        float cb = __expf(mo - mn);
        float rl = 1.0f / (lsum * ca + lo_ * cb);
        #pragma unroll
        for (int dvt = 0; dvt < 4; ++dvt)
            #pragma unroll
            for (int r = 0; r < 16; ++r)
                o[dvt][r] = (o[dvt][r] * ca + obuf[(dvt * 16 + r) * 64 + l] * cb) * rl;
    }
    __syncthreads();
    // -------- transpose O^T -> row-major via LDS, coalesced store --------
    float* tbuf = (float*)lds;                  // [32][132] f32
    if (w == 0) {
        #pragma unroll
        for (int dvt = 0; dvt < 4; ++dvt)
            #pragma unroll
            for (int r = 0; r < 16; ++r) {
                int dv = dvt * 32 + (r & 3) + 8 * (r >> 2) + 4 * hi;
                tbuf[lq * 132 + dv] = o[dvt][r];
            }
    }
    __syncthreads();
    const size_t obase = (size_t)(b * SEQ + qt * 32) * DKV;
    int row = t >> 3, c0 = (t & 7) * 16;
    #pragma unroll
    for (int i = 0; i < 4; ++i) {
        float4 v = *(const float4*)(tbuf + row * 132 + c0 + i * 4);
        *(float4*)(out + obase + row * 128 + c0 + i * 4) = v;
    }
}

extern "C" void kernel_launch(void* const* d_in, const int* in_sizes, int n_in,
                              void* d_out, int out_size, void* d_ws, size_t ws_size,
                              hipStream_t stream) {
    const float* X  = (const float*)d_in[0];
    const float* Wq = (const float*)d_in[1];
    const float* bq = (const float*)d_in[2];
    const float* Wk = (const float*)d_in[3];
    const float* bk = (const float*)d_in[4];
    const float* Wv = (const float*)d_in[5];
    const float* bv = (const float*)d_in[6];
    float* out = (float*)d_out;

    const size_t nqe = (size_t)NB * SEQ * DKV;            // 2M elements
    _Float16* Qh  = (_Float16*)d_ws;
    _Float16* Kh  = Qh  + nqe;
    _Float16* VTh = Kh  + nqe;
    _Float16* WTh = VTh + nqe;                            // 3*128*1024 f16

    prep_wt<<<(3 * 1024 * 128) / 256, 256, 0, stream>>>(Wq, Wk, Wv, WTh);
    qkv_proj<<<(NB * SEQ / 64) * 3, 256, 0, stream>>>(X, bq, bk, bv, WTh, Qh, Kh, VTh);
    attn_kernel<<<NB * 128, 256, 0, stream>>>(Qh, Kh, VTh, out);
}